// Round 1
// 8992.675 us; speedup vs baseline: 1.0631x; 1.0631x over previous
//
#include <hip/hip_runtime.h>
#include <math.h>

// MultilayerLSTM: B=16, S=512, D_IN=512, D_H=1024, D_OUT=2, VOCAB=32000
// Round 3: fence-free grid barrier. The round-2 kernel spent ~6 us/step in
// agent-scope fences (buffer_wbl2 + buffer_inv = full L2 writeback+invalidate
// per step per block) around a contended atomic counter. Replaced with:
//   - H bf16 stores as sc0/sc1 write-through (__hip_atomic_store relaxed agent)
//   - flag-array barrier: block i stores step number to flags[i]; wave 0 lanes
//     poll all 64 flags (one lane each) + __all ballot. No fences at all;
//     __syncthreads' implicit vmcnt(0) is the release, and hb16 lines are
//     written exactly once (write-through) so cached reads can't be stale.
//   - xp prefetch (next step's row loads issued before the barrier wait)
//   - 2-accumulator MFMA chain (halves dependent-MFMA latency)
//   - Pre[4][16][17] padding (kills 4-way LDS write conflict)

#define BB   16
#define SLEN 512
#define DIN  512
#define DH   1024

typedef __attribute__((ext_vector_type(8))) short short8;
typedef __attribute__((ext_vector_type(4))) float f32x4;

__device__ inline unsigned short f2bfbits(float x) {
  union { float f; unsigned u; } v; v.f = x;
  unsigned r = v.u + 0x7FFF + ((v.u >> 16) & 1);  // RNE
  return (unsigned short)(r >> 16);
}

// ---------------- zero flags ----------------
__global__ void zero_cnt_kernel(unsigned* cnt) {
  if (threadIdx.x < 128) cnt[threadIdx.x] = 0;
}

// ---------------- embedding gather ----------------
__global__ __launch_bounds__(256) void embed_kernel(const int* __restrict__ tokens,
                                                    const float* __restrict__ emb,
                                                    float* __restrict__ x0) {
  int idx = blockIdx.x * 256 + threadIdx.x;  // over 8192*128 float4s
  int r = idx >> 7, d4 = idx & 127;
  int tok = tokens[r];
  const float4* src = (const float4*)emb + (((size_t)tok) << 7) + d4;
  ((float4*)x0)[(((size_t)r) << 7) + d4] = *src;
}

// ---------------- xproj GEMM: C[M][4096] = A[M][K] @ W_g[K][1024] + b_g ----------------
__global__ __launch_bounds__(256) void xproj_kernel(
    const float* __restrict__ A, int K,
    const float* __restrict__ Wi, const float* __restrict__ Wf,
    const float* __restrict__ Wg, const float* __restrict__ Wo,
    const float* __restrict__ bi, const float* __restrict__ bf,
    const float* __restrict__ bg, const float* __restrict__ bo,
    float* __restrict__ Cout)
{
  __shared__ float As[8][128];
  __shared__ float Bs[8][128];
  const int tid = threadIdx.x;
  const int bn = blockIdx.x;   // 0..31
  const int bm = blockIdx.y;   // 0..63
  const int m0 = bm * 128;
  const int n0 = bn * 128;
  const int g = n0 >> 10;
  const float* W    = (g == 0) ? Wi : (g == 1) ? Wf : (g == 2) ? Wg : Wo;
  const float* bias = (g == 0) ? bi : (g == 1) ? bf : (g == 2) ? bg : bo;
  const int col0 = n0 & 1023;
  const int tx = tid & 15, ty = tid >> 4;
  const int lr = tid >> 1, lh = tid & 1;          // A-tile loader
  const int lk = tid >> 5, ln = (tid & 31) << 2;  // B-tile loader

  float acc[8][8];
#pragma unroll
  for (int i = 0; i < 8; ++i)
#pragma unroll
    for (int j = 0; j < 8; ++j) acc[i][j] = 0.f;

  for (int k0 = 0; k0 < K; k0 += 8) {
    float4 av = *(const float4*)(A + (size_t)(m0 + lr) * K + k0 + lh * 4);
    float4 bv = *(const float4*)(W + (size_t)(k0 + lk) * 1024 + col0 + ln);
    As[lh * 4 + 0][lr] = av.x;
    As[lh * 4 + 1][lr] = av.y;
    As[lh * 4 + 2][lr] = av.z;
    As[lh * 4 + 3][lr] = av.w;
    *(float4*)&Bs[lk][ln] = bv;
    __syncthreads();
#pragma unroll
    for (int p = 0; p < 8; ++p) {
      float a[8], b[8];
      *(float4*)&a[0] = *(const float4*)&As[p][ty * 8];
      *(float4*)&a[4] = *(const float4*)&As[p][ty * 8 + 4];
      *(float4*)&b[0] = *(const float4*)&Bs[p][tx * 4];
      *(float4*)&b[4] = *(const float4*)&Bs[p][64 + tx * 4];
#pragma unroll
      for (int i = 0; i < 8; ++i)
#pragma unroll
        for (int j = 0; j < 8; ++j) acc[i][j] += a[i] * b[j];
    }
    __syncthreads();
  }
  float4 bA = *(const float4*)(bias + col0 + tx * 4);
  float4 bB = *(const float4*)(bias + col0 + 64 + tx * 4);
#pragma unroll
  for (int i = 0; i < 8; ++i) {
    int m = m0 + ty * 8 + i;
    float* crow = Cout + (((size_t)m) << 12) + n0;
    float4 o1 = make_float4(acc[i][0] + bA.x, acc[i][1] + bA.y, acc[i][2] + bA.z, acc[i][3] + bA.w);
    float4 o2 = make_float4(acc[i][4] + bB.x, acc[i][5] + bB.y, acc[i][6] + bB.z, acc[i][7] + bB.w);
    *(float4*)(crow + tx * 4) = o1;
    *(float4*)(crow + 64 + tx * 4) = o2;
  }
}

// ---------------- MFMA persistent LSTM recurrence ----------------
// 64 blocks x 256 threads. Block owns hidden cols c0 = blockIdx.x*16 .. +15.
// Wave g (tid>>6) = gate g. Per step per wave: 32x mfma_f32_16x16x32_bf16
// (A = H(t-1) [16 x 1024] bf16; B = persistent W-frags in VGPRs).
// hb16 lines written ONCE each (write-through sc0/sc1), read the next step:
// cached reads can never observe stale data (kernel-launch acquire already
// invalidated any aliased lines), so no acquire fence / L2 inv is needed.
__global__ __launch_bounds__(256, 1) void lstm_rec_mfma(
    const float* __restrict__ xp,
    const float* __restrict__ Wi, const float* __restrict__ Wf,
    const float* __restrict__ Wg, const float* __restrict__ Wo,
    int D,
    short* __restrict__ hb16,        // bf16 bits [t][b][1024]
    float* __restrict__ hf32,        // f32 [b][t][1024]
    unsigned* __restrict__ flags)    // 64 step-flags, pre-zeroed
{
  __shared__ float Pre[4][16][17];   // +1 pad: conflict-free q-strided writes
  const int tid  = threadIdx.x;
  const int wv   = tid >> 6;         // gate
  const int lane = tid & 63;
  const int q    = lane >> 4;        // quad
  const int n    = lane & 15;        // output col within tile
  const int c0   = blockIdx.x << 4;
  const float* Wsel = (wv == 0) ? Wi : (wv == 1) ? Wf : (wv == 2) ? Wg : Wo;

  // persistent B-frags: wfrag[kk] holds W[D + kk*32 + q*8 + j][c0+n], j=0..7
  short8 wfrag[32];
#pragma unroll
  for (int kk = 0; kk < 32; ++kk) {
#pragma unroll
    for (int j = 0; j < 8; ++j) {
      float w = Wsel[(size_t)(D + kk * 32 + q * 8 + j) * 1024 + c0 + n];
      wfrag[kk][j] = (short)f2bfbits(w);
    }
  }

  const int cb = tid >> 4, cc = tid & 15;  // cell-update mapping
  float Creg = 0.f;

  // xp: element ((q*4+r)*SLEN + t)*4096 + (wv<<10) + c0 + n ; prefetch 1 step
  const float* xpb = xp + ((size_t)wv << 10) + c0 + n;
  f32x4 xpn;
#pragma unroll
  for (int r = 0; r < 4; ++r)
    xpn[r] = xpb[(size_t)((q * 4 + r) * SLEN) << 12 >> 0];  // t = 0

  for (int t = 0; t < SLEN; ++t) {
    f32x4 acc = xpn;                 // bias already folded by xproj
    f32x4 acc2 = {0.f, 0.f, 0.f, 0.f};

    // prefetch next step's xp row (independent of everything below)
    if (t + 1 < SLEN) {
#pragma unroll
      for (int r = 0; r < 4; ++r)
        xpn[r] = xpb[((size_t)((q * 4 + r) * SLEN + t + 1)) << 12];
    }

    if (t > 0) {
      const short* hrow = hb16 + (((size_t)(t - 1)) << 14) + n * 1024 + q * 8;
#pragma unroll
      for (int kk = 0; kk < 32; kk += 2) {
        short8 af0 = *(const short8*)(hrow + kk * 32);
        short8 af1 = *(const short8*)(hrow + kk * 32 + 32);
        acc  = __builtin_amdgcn_mfma_f32_16x16x32_bf16(af0, wfrag[kk],     acc,  0, 0, 0);
        acc2 = __builtin_amdgcn_mfma_f32_16x16x32_bf16(af1, wfrag[kk + 1], acc2, 0, 0, 0);
      }
#pragma unroll
      for (int r = 0; r < 4; ++r) acc[r] += acc2[r];
    }

    // exchange preacts via LDS
#pragma unroll
    for (int r = 0; r < 4; ++r) Pre[wv][q * 4 + r][n] = acc[r];
    __syncthreads();

    // cell update: thread (cb, cc)
    float pI = Pre[0][cb][cc];
    float pF = Pre[1][cb][cc];
    float pG = Pre[2][cb][cc];
    float pO = Pre[3][cb][cc];
    float gI = 1.f / (1.f + __expf(-pI));
    float gF = 1.f / (1.f + __expf(-pF));
    float gG = tanhf(pG);
    float gO = 1.f / (1.f + __expf(-pO));
    Creg = gF * Creg + gI * gG;
    float h = gO * tanhf(Creg);

    // f32 store [b][t][k] for xproj(l1)/head (normal cached; flushed at kernel end)
    hf32[(((size_t)(cb * SLEN + t)) << 10) + c0 + cc] = h;
    // bf16 store [t][b][k]: pack pairs via shfl, write-through to coherence point
    unsigned mybits = (unsigned)f2bfbits(h);
    unsigned nbbits = (unsigned)__shfl_xor((int)mybits, 1, 64);
    if ((cc & 1) == 0) {
      unsigned pk = mybits | (nbbits << 16);
      __hip_atomic_store((unsigned*)(hb16 + (((size_t)(t * 16 + cb)) << 10) + c0 + cc), pk,
                         __ATOMIC_RELAXED, __HIP_MEMORY_SCOPE_AGENT);
    }
    // implicit s_waitcnt vmcnt(0) in every wave before s_barrier: all H stores
    // of this block are at the device coherence point after this barrier.
    __syncthreads();

    // fence-free flag barrier (64 blocks)
    if (t + 1 < SLEN) {
      if (tid == 0)
        __hip_atomic_store(&flags[blockIdx.x], (unsigned)(t + 1),
                           __ATOMIC_RELAXED, __HIP_MEMORY_SCOPE_AGENT);
      if (tid < 64) {
        const unsigned tgt = (unsigned)(t + 1);
        while (true) {
          unsigned v = __hip_atomic_load(&flags[tid], __ATOMIC_RELAXED,
                                         __HIP_MEMORY_SCOPE_AGENT);
          if (__all((int)(v >= tgt))) break;
          __builtin_amdgcn_s_sleep(1);
        }
      }
      __syncthreads();
    }
  }
}

// ---------------- FC head + log_softmax (D_OUT=2) ----------------
__global__ __launch_bounds__(256) void head_kernel(const float* __restrict__ h,
                                                   const float* __restrict__ Wfc,
                                                   const float* __restrict__ bfc,
                                                   float* __restrict__ out)
{
  const int lane = threadIdx.x & 63;
  const int row = blockIdx.x * 4 + (threadIdx.x >> 6);
  const float* hr = h + (((size_t)row) << 10);
  float s0 = 0.f, s1 = 0.f;
#pragma unroll
  for (int i = 0; i < 16; ++i) {
    int k = lane + i * 64;
    float hv = hr[k];
    float2 w = *(const float2*)(Wfc + 2 * k);
    s0 += hv * w.x;
    s1 += hv * w.y;
  }
#pragma unroll
  for (int off = 32; off > 0; off >>= 1) {
    s0 += __shfl_down(s0, off);
    s1 += __shfl_down(s1, off);
  }
  if (lane == 0) {
    s0 += bfc[0];
    s1 += bfc[1];
    float m = fmaxf(s0, s1);
    float lse = m + logf(expf(s0 - m) + expf(s1 - m));
    out[((size_t)row << 1) + 0] = s0 - lse;
    out[((size_t)row << 1) + 1] = s1 - lse;
  }
}

extern "C" void kernel_launch(void* const* d_in, const int* in_sizes, int n_in,
                              void* d_out, int out_size, void* d_ws, size_t ws_size,
                              hipStream_t stream)
{
  const int*   tokens = (const int*)d_in[0];
  const float* emb = (const float*)d_in[1];
  const float* W0i = (const float*)d_in[2];
  const float* b0i = (const float*)d_in[3];
  const float* W0f = (const float*)d_in[4];
  const float* b0f = (const float*)d_in[5];
  const float* W0g = (const float*)d_in[6];
  const float* b0g = (const float*)d_in[7];
  const float* W0o = (const float*)d_in[8];
  const float* b0o = (const float*)d_in[9];
  const float* W1i = (const float*)d_in[10];
  const float* b1i = (const float*)d_in[11];
  const float* W1f = (const float*)d_in[12];
  const float* b1f = (const float*)d_in[13];
  const float* W1g = (const float*)d_in[14];
  const float* b1g = (const float*)d_in[15];
  const float* W1o = (const float*)d_in[16];
  const float* b1o = (const float*)d_in[17];
  const float* Wfc = (const float*)d_in[18];
  const float* bfc = (const float*)d_in[19];
  float* out = (float*)d_out;

  float* ws = (float*)d_ws;
  float* x0 = ws;                               // 8192*512 f32; later aliased as bf16 h [t][b][1024]
  float* h0 = x0 + (size_t)8192 * 512;          // 8192*1024 f32 [b][t][k] (both layers)
  float* xp = h0 + (size_t)8192 * 1024;         // 8192*4096 f32 (both layers)
  unsigned* cnt = (unsigned*)(xp + (size_t)8192 * 4096);  // 128 u32 flags
  short* hb16 = (short*)x0;                     // 512*16*1024 bf16 = 16 MB (aliases x0)

  zero_cnt_kernel<<<1, 128, 0, stream>>>(cnt);
  embed_kernel<<<4096, 256, 0, stream>>>(tokens, emb, x0);
  xproj_kernel<<<dim3(32, 64), 256, 0, stream>>>(x0, 512,  W0i, W0f, W0g, W0o,
                                                 b0i, b0f, b0g, b0o, xp);
  // rec(l0): writes hb16 over x0 (x0 fully consumed by xproj above)
  lstm_rec_mfma<<<64, 256, 0, stream>>>(xp, W0i, W0f, W0g, W0o, 512, hb16, h0, cnt);
  xproj_kernel<<<dim3(32, 64), 256, 0, stream>>>(h0, 1024, W1i, W1f, W1g, W1o,
                                                 b1i, b1f, b1g, b1o, xp);
  lstm_rec_mfma<<<64, 256, 0, stream>>>(xp, W1i, W1f, W1g, W1o, 1024, hb16, h0, cnt + 64);
  head_kernel<<<2048, 256, 0, stream>>>(h0, Wfc, bfc, out);
}

// Round 2
// 7445.208 us; speedup vs baseline: 1.2840x; 1.2078x over previous
//
#include <hip/hip_runtime.h>
#include <math.h>

// MultilayerLSTM: B=16, S=512, D_IN=512, D_H=1024, D_OUT=2, VOCAB=32000
// Round 4: layer-pipelined fused recurrence. Round-3 showed per-step cost
// (~7.5us) is irreducible cross-XCD latency (sc1 drain -> flag -> poll -> L3
// read chain), so this round halves the NUMBER of serial rounds instead:
//   - One persistent kernel, 128 blocks: blk 0..63 = layer 0, 64..127 = layer 1
//     running concurrently, layer 1 lagging one step (flag0/flag1 arrays).
//   - Layer 1 consumes h0(t) as bf16 MFMA A-frags (K=2048 over [h0,h1]),
//     eliminating the second xproj GEMM (~500us) and all hf32 traffic.
//   - FC head (1024->2) folded into layer-1 blocks per step: 16-lane shuffle
//     reduce -> part[row][64] partials; tiny finalize kernel does the 64-way
//     sum + bias + log_softmax.
//   - Layer-0 lead over layer-1 capped at LEAD=8 steps (bounded write-ahead
//     window; 32KB row stride >> 4KB page so no prefetch staleness).
// Serial rounds: 1024 -> ~513.

#define BB    16
#define SLEN  512
#define DH    1024
#define NBLK0 64
#define LEAD  8

typedef __attribute__((ext_vector_type(8))) short short8;
typedef __attribute__((ext_vector_type(4))) float f32x4;

__device__ inline unsigned short f2bfbits(float x) {
  union { float f; unsigned u; } v; v.f = x;
  unsigned r = v.u + 0x7FFF + ((v.u >> 16) & 1);  // RNE
  return (unsigned short)(r >> 16);
}

// ---------------- zero flags ----------------
__global__ void zero_cnt_kernel(unsigned* cnt) {
  if (threadIdx.x < 128) cnt[threadIdx.x] = 0;
}

// ---------------- embedding gather ----------------
__global__ __launch_bounds__(256) void embed_kernel(const int* __restrict__ tokens,
                                                    const float* __restrict__ emb,
                                                    float* __restrict__ x0) {
  int idx = blockIdx.x * 256 + threadIdx.x;  // over 8192*128 float4s
  int r = idx >> 7, d4 = idx & 127;
  int tok = tokens[r];
  const float4* src = (const float4*)emb + (((size_t)tok) << 7) + d4;
  ((float4*)x0)[(((size_t)r) << 7) + d4] = *src;
}

// ---------------- xproj GEMM (layer 0 only): C[M][4096] = A[M][512] @ W_g + b_g ----------------
__global__ __launch_bounds__(256) void xproj_kernel(
    const float* __restrict__ A, int K,
    const float* __restrict__ Wi, const float* __restrict__ Wf,
    const float* __restrict__ Wg, const float* __restrict__ Wo,
    const float* __restrict__ bi, const float* __restrict__ bf,
    const float* __restrict__ bg, const float* __restrict__ bo,
    float* __restrict__ Cout)
{
  __shared__ float As[8][128];
  __shared__ float Bs[8][128];
  const int tid = threadIdx.x;
  const int bn = blockIdx.x;   // 0..31
  const int bm = blockIdx.y;   // 0..63
  const int m0 = bm * 128;
  const int n0 = bn * 128;
  const int g = n0 >> 10;
  const float* W    = (g == 0) ? Wi : (g == 1) ? Wf : (g == 2) ? Wg : Wo;
  const float* bias = (g == 0) ? bi : (g == 1) ? bf : (g == 2) ? bg : bo;
  const int col0 = n0 & 1023;
  const int tx = tid & 15, ty = tid >> 4;
  const int lr = tid >> 1, lh = tid & 1;          // A-tile loader
  const int lk = tid >> 5, ln = (tid & 31) << 2;  // B-tile loader

  float acc[8][8];
#pragma unroll
  for (int i = 0; i < 8; ++i)
#pragma unroll
    for (int j = 0; j < 8; ++j) acc[i][j] = 0.f;

  for (int k0 = 0; k0 < K; k0 += 8) {
    float4 av = *(const float4*)(A + (size_t)(m0 + lr) * K + k0 + lh * 4);
    float4 bv = *(const float4*)(W + (size_t)(k0 + lk) * 1024 + col0 + ln);
    As[lh * 4 + 0][lr] = av.x;
    As[lh * 4 + 1][lr] = av.y;
    As[lh * 4 + 2][lr] = av.z;
    As[lh * 4 + 3][lr] = av.w;
    *(float4*)&Bs[lk][ln] = bv;
    __syncthreads();
#pragma unroll
    for (int p = 0; p < 8; ++p) {
      float a[8], b[8];
      *(float4*)&a[0] = *(const float4*)&As[p][ty * 8];
      *(float4*)&a[4] = *(const float4*)&As[p][ty * 8 + 4];
      *(float4*)&b[0] = *(const float4*)&Bs[p][tx * 4];
      *(float4*)&b[4] = *(const float4*)&Bs[p][64 + tx * 4];
#pragma unroll
      for (int i = 0; i < 8; ++i)
#pragma unroll
        for (int j = 0; j < 8; ++j) acc[i][j] += a[i] * b[j];
    }
    __syncthreads();
  }
  float4 bA = *(const float4*)(bias + col0 + tx * 4);
  float4 bB = *(const float4*)(bias + col0 + 64 + tx * 4);
#pragma unroll
  for (int i = 0; i < 8; ++i) {
    int m = m0 + ty * 8 + i;
    float* crow = Cout + (((size_t)m) << 12) + n0;
    float4 o1 = make_float4(acc[i][0] + bA.x, acc[i][1] + bA.y, acc[i][2] + bA.z, acc[i][3] + bA.w);
    float4 o2 = make_float4(acc[i][4] + bB.x, acc[i][5] + bB.y, acc[i][6] + bB.z, acc[i][7] + bB.w);
    *(float4*)(crow + tx * 4) = o1;
    *(float4*)(crow + 64 + tx * 4) = o2;
  }
}

// ---------------- fused pipelined 2-layer LSTM recurrence ----------------
// blk 0..63: layer 0 (cols blk*16). blk 64..127: layer 1 (cols (blk-64)*16).
// h0b16/h1b16: bf16 [t][b][1024], written once per line with sc0/sc1
// write-through (agent-relaxed atomic store); readers use plain cached loads
// only after the producer's flag is visible (line written before first read).
// flags[0..63] = layer-0 step counters, flags[64..127] = layer-1.
__global__ __launch_bounds__(256, 1) void lstm_pipe(
    const float* __restrict__ xp,
    const float* __restrict__ W0i, const float* __restrict__ W0f,
    const float* __restrict__ W0g, const float* __restrict__ W0o,
    const float* __restrict__ W1i, const float* __restrict__ W1f,
    const float* __restrict__ W1g, const float* __restrict__ W1o,
    const float* __restrict__ b1i, const float* __restrict__ b1f,
    const float* __restrict__ b1g, const float* __restrict__ b1o,
    const float* __restrict__ Wfc,
    short* __restrict__ h0b16,
    short* __restrict__ h1b16,
    float2* __restrict__ part,       // [b*512+t][64] per-block head partials
    unsigned* __restrict__ flags)
{
  __shared__ float Pre[4][16][17];
  const int tid  = threadIdx.x;
  const int wv   = tid >> 6;         // gate
  const int lane = tid & 63;
  const int q    = lane >> 4;
  const int n    = lane & 15;
  const int cb   = tid >> 4, cc = tid & 15;  // cell-update mapping

  if (blockIdx.x < NBLK0) {
    // ================= layer 0 =================
    const int c0 = blockIdx.x << 4;
    const float* Wsel = (wv == 0) ? W0i : (wv == 1) ? W0f : (wv == 2) ? W0g : W0o;
    short8 wfrag[32];
#pragma unroll
    for (int kk = 0; kk < 32; ++kk)
#pragma unroll
      for (int j = 0; j < 8; ++j)
        wfrag[kk][j] = (short)f2bfbits(Wsel[(size_t)(512 + kk * 32 + q * 8 + j) * 1024 + c0 + n]);

    float Creg = 0.f;
    const float* xpb = xp + ((size_t)wv << 10) + c0 + n;
    f32x4 xpn;
#pragma unroll
    for (int r = 0; r < 4; ++r)
      xpn[r] = xpb[((size_t)((q * 4 + r) * SLEN)) << 12];

    for (int t = 0; t < SLEN; ++t) {
      f32x4 acc = xpn;
      f32x4 acc2 = {0.f, 0.f, 0.f, 0.f};
      if (t + 1 < SLEN) {
#pragma unroll
        for (int r = 0; r < 4; ++r)
          xpn[r] = xpb[((size_t)((q * 4 + r) * SLEN + t + 1)) << 12];
      }
      if (t > 0) {
        const short* hrow = h0b16 + (((size_t)(t - 1)) << 14) + n * 1024 + q * 8;
#pragma unroll
        for (int kk = 0; kk < 32; kk += 2) {
          short8 a0 = *(const short8*)(hrow + kk * 32);
          short8 a1 = *(const short8*)(hrow + kk * 32 + 32);
          acc  = __builtin_amdgcn_mfma_f32_16x16x32_bf16(a0, wfrag[kk],     acc,  0, 0, 0);
          acc2 = __builtin_amdgcn_mfma_f32_16x16x32_bf16(a1, wfrag[kk + 1], acc2, 0, 0, 0);
        }
#pragma unroll
        for (int r = 0; r < 4; ++r) acc[r] += acc2[r];
      }
#pragma unroll
      for (int r = 0; r < 4; ++r) Pre[wv][q * 4 + r][n] = acc[r];
      __syncthreads();

      float pI = Pre[0][cb][cc], pF = Pre[1][cb][cc];
      float pG = Pre[2][cb][cc], pO = Pre[3][cb][cc];
      float gI = 1.f / (1.f + __expf(-pI));
      float gF = 1.f / (1.f + __expf(-pF));
      float gG = tanhf(pG);
      float gO = 1.f / (1.f + __expf(-pO));
      Creg = gF * Creg + gI * gG;
      float h = gO * tanhf(Creg);

      unsigned mybits = (unsigned)f2bfbits(h);
      unsigned nbbits = (unsigned)__shfl_xor((int)mybits, 1, 64);
      if ((cc & 1) == 0) {
        unsigned pk = mybits | (nbbits << 16);
        __hip_atomic_store((unsigned*)(h0b16 + (((size_t)(t * 16 + cb)) << 10) + c0 + cc), pk,
                           __ATOMIC_RELAXED, __HIP_MEMORY_SCOPE_AGENT);
      }
      __syncthreads();  // implicit vmcnt(0): stores at coherence point

      if (tid == 0)
        __hip_atomic_store(&flags[blockIdx.x], (unsigned)(t + 1),
                           __ATOMIC_RELAXED, __HIP_MEMORY_SCOPE_AGENT);
      if (t + 1 < SLEN) {
        if (tid < 64) {
          const unsigned tgt = (unsigned)(t + 1);
          while (true) {
            unsigned v0 = __hip_atomic_load(&flags[tid], __ATOMIC_RELAXED,
                                            __HIP_MEMORY_SCOPE_AGENT);
            unsigned v1 = __hip_atomic_load(&flags[64 + tid], __ATOMIC_RELAXED,
                                            __HIP_MEMORY_SCOPE_AGENT);
            // own-layer dep + cap lead over layer 1 at LEAD steps
            if (__all((int)(v0 >= tgt && v1 + LEAD >= tgt))) break;
          }
        }
        __syncthreads();
      }
    }
  } else {
    // ================= layer 1 =================
    const int blk1 = blockIdx.x - NBLK0;
    const int c0 = blk1 << 4;
    const float* Wsel = (wv == 0) ? W1i : (wv == 1) ? W1f : (wv == 2) ? W1g : W1o;
    const float* bsel = (wv == 0) ? b1i : (wv == 1) ? b1f : (wv == 2) ? b1g : b1o;
    short8 wfx[32], wfh[32];
#pragma unroll
    for (int kk = 0; kk < 32; ++kk)
#pragma unroll
      for (int j = 0; j < 8; ++j) {
        wfx[kk][j] = (short)f2bfbits(Wsel[(size_t)(kk * 32 + q * 8 + j) * 1024 + c0 + n]);
        wfh[kk][j] = (short)f2bfbits(Wsel[(size_t)(1024 + kk * 32 + q * 8 + j) * 1024 + c0 + n]);
      }
    const float bcol = bsel[c0 + n];
    const float wfc0 = Wfc[(c0 + cc) * 2 + 0];
    const float wfc1 = Wfc[(c0 + cc) * 2 + 1];
    float Creg = 0.f;

    for (int t = 0; t < SLEN; ++t) {
      // wait for h0(t) (flag0 >= t+1) and h1(t-1) (flag1 >= t)
      if (tid < 64) {
        const unsigned tgt0 = (unsigned)(t + 1);
        const unsigned tgt1 = (unsigned)t;
        while (true) {
          unsigned v0 = __hip_atomic_load(&flags[tid], __ATOMIC_RELAXED,
                                          __HIP_MEMORY_SCOPE_AGENT);
          unsigned v1 = __hip_atomic_load(&flags[64 + tid], __ATOMIC_RELAXED,
                                          __HIP_MEMORY_SCOPE_AGENT);
          if (__all((int)(v0 >= tgt0 && v1 >= tgt1))) break;
        }
      }
      __syncthreads();

      f32x4 acc, acc2 = {0.f, 0.f, 0.f, 0.f};
#pragma unroll
      for (int r = 0; r < 4; ++r) acc[r] = bcol;

      const short* xrow = h0b16 + (((size_t)t) << 14) + n * 1024 + q * 8;
#pragma unroll
      for (int kk = 0; kk < 32; kk += 2) {
        short8 a0 = *(const short8*)(xrow + kk * 32);
        short8 a1 = *(const short8*)(xrow + kk * 32 + 32);
        acc  = __builtin_amdgcn_mfma_f32_16x16x32_bf16(a0, wfx[kk],     acc,  0, 0, 0);
        acc2 = __builtin_amdgcn_mfma_f32_16x16x32_bf16(a1, wfx[kk + 1], acc2, 0, 0, 0);
      }
      if (t > 0) {
        const short* hrow = h1b16 + (((size_t)(t - 1)) << 14) + n * 1024 + q * 8;
#pragma unroll
        for (int kk = 0; kk < 32; kk += 2) {
          short8 a0 = *(const short8*)(hrow + kk * 32);
          short8 a1 = *(const short8*)(hrow + kk * 32 + 32);
          acc  = __builtin_amdgcn_mfma_f32_16x16x32_bf16(a0, wfh[kk],     acc,  0, 0, 0);
          acc2 = __builtin_amdgcn_mfma_f32_16x16x32_bf16(a1, wfh[kk + 1], acc2, 0, 0, 0);
        }
      }
#pragma unroll
      for (int r = 0; r < 4; ++r) acc[r] += acc2[r];

#pragma unroll
      for (int r = 0; r < 4; ++r) Pre[wv][q * 4 + r][n] = acc[r];
      __syncthreads();

      float pI = Pre[0][cb][cc], pF = Pre[1][cb][cc];
      float pG = Pre[2][cb][cc], pO = Pre[3][cb][cc];
      float gI = 1.f / (1.f + __expf(-pI));
      float gF = 1.f / (1.f + __expf(-pF));
      float gG = tanhf(pG);
      float gO = 1.f / (1.f + __expf(-pO));
      Creg = gF * Creg + gI * gG;
      float h = gO * tanhf(Creg);

      // head partial: sum over this block's 16 cols for row (b=cb, t)
      float p0 = h * wfc0, p1 = h * wfc1;
#pragma unroll
      for (int m = 1; m < 16; m <<= 1) {
        p0 += __shfl_xor(p0, m, 64);
        p1 += __shfl_xor(p1, m, 64);
      }
      if (cc == 0)
        part[(size_t)(cb * SLEN + t) * 64 + blk1] = make_float2(p0, p1);

      unsigned mybits = (unsigned)f2bfbits(h);
      unsigned nbbits = (unsigned)__shfl_xor((int)mybits, 1, 64);
      if ((cc & 1) == 0) {
        unsigned pk = mybits | (nbbits << 16);
        __hip_atomic_store((unsigned*)(h1b16 + (((size_t)(t * 16 + cb)) << 10) + c0 + cc), pk,
                           __ATOMIC_RELAXED, __HIP_MEMORY_SCOPE_AGENT);
      }
      __syncthreads();  // drains stores

      if (tid == 0)
        __hip_atomic_store(&flags[64 + blk1], (unsigned)(t + 1),
                           __ATOMIC_RELAXED, __HIP_MEMORY_SCOPE_AGENT);
    }
  }
}

// ---------------- finalize: 64-way partial sum + bias + log_softmax ----------------
__global__ __launch_bounds__(256) void finalize_kernel(const float2* __restrict__ part,
                                                       const float* __restrict__ bfc,
                                                       float* __restrict__ out)
{
  const int lane = threadIdx.x & 63;
  const int row = blockIdx.x * 4 + (threadIdx.x >> 6);
  float2 v = part[(size_t)row * 64 + lane];
  float s0 = v.x, s1 = v.y;
#pragma unroll
  for (int off = 32; off > 0; off >>= 1) {
    s0 += __shfl_down(s0, off);
    s1 += __shfl_down(s1, off);
  }
  if (lane == 0) {
    s0 += bfc[0];
    s1 += bfc[1];
    float m = fmaxf(s0, s1);
    float lse = m + logf(expf(s0 - m) + expf(s1 - m));
    out[((size_t)row << 1) + 0] = s0 - lse;
    out[((size_t)row << 1) + 1] = s1 - lse;
  }
}

extern "C" void kernel_launch(void* const* d_in, const int* in_sizes, int n_in,
                              void* d_out, int out_size, void* d_ws, size_t ws_size,
                              hipStream_t stream)
{
  const int*   tokens = (const int*)d_in[0];
  const float* emb = (const float*)d_in[1];
  const float* W0i = (const float*)d_in[2];
  const float* b0i = (const float*)d_in[3];
  const float* W0f = (const float*)d_in[4];
  const float* b0f = (const float*)d_in[5];
  const float* W0g = (const float*)d_in[6];
  const float* b0g = (const float*)d_in[7];
  const float* W0o = (const float*)d_in[8];
  const float* b0o = (const float*)d_in[9];
  const float* W1i = (const float*)d_in[10];
  const float* b1i = (const float*)d_in[11];
  const float* W1f = (const float*)d_in[12];
  const float* b1f = (const float*)d_in[13];
  const float* W1g = (const float*)d_in[14];
  const float* b1g = (const float*)d_in[15];
  const float* W1o = (const float*)d_in[16];
  const float* b1o = (const float*)d_in[17];
  const float* Wfc = (const float*)d_in[18];
  const float* bfc = (const float*)d_in[19];
  float* out = (float*)d_out;

  float* ws = (float*)d_ws;
  float* x0 = ws;                               // 16MB embed out; aliased as h0b16
  float* hA = x0 + (size_t)8192 * 512;          // 32MB region: h1b16 (16MB) + part (4MB)
  float* xp = hA + (size_t)8192 * 1024;         // 128MB layer-0 x-preacts
  unsigned* flags = (unsigned*)(xp + (size_t)8192 * 4096);
  short*  h0b16 = (short*)x0;                   // bf16 [t][b][1024]
  short*  h1b16 = (short*)hA;                   // bf16 [t][b][1024]
  float2* part  = (float2*)(hA + (size_t)8192 * 512);  // [8192][64] float2

  zero_cnt_kernel<<<1, 128, 0, stream>>>(flags);
  embed_kernel<<<4096, 256, 0, stream>>>(tokens, emb, x0);
  xproj_kernel<<<dim3(32, 64), 256, 0, stream>>>(x0, 512, W0i, W0f, W0g, W0o,
                                                 b0i, b0f, b0g, b0o, xp);
  lstm_pipe<<<128, 256, 0, stream>>>(xp,
                                     W0i, W0f, W0g, W0o,
                                     W1i, W1f, W1g, W1o,
                                     b1i, b1f, b1g, b1o,
                                     Wfc, h0b16, h1b16, part, flags);
  finalize_kernel<<<2048, 256, 0, stream>>>(part, bfc, out);
}

// Round 3
// 5849.606 us; speedup vs baseline: 1.6343x; 1.2728x over previous
//
#include <hip/hip_runtime.h>
#include <math.h>

// MultilayerLSTM: B=16, S=512, D_IN=512, D_H=1024, D_OUT=2, VOCAB=32000
// Round 5: fix layer-1 VGPR spill (round-4: VGPR pegged 256, FETCH +106MB =
// scratch reload on the serial critical path every step).
//   - lstm_pipe blocks are now 512 threads = 8 waves: wave = (gate, K-half).
//     l1 waves hold 32 weight frags (128 VGPR), l0 waves 16 (64 VGPR). No spill.
//   - Pre[8][16][17]: cell update sums the two K-half partial preacts.
//   - s_sleep(1) restored in all poll loops (round-4 dropped it).
//   - LEAD cap removed: h0b16 is fully materialized per-t (no overwrite), so
//     layer 0 never needs to look at layer-1 flags; halves poll traffic.
// Geometry: blk 0..63 = layer 0, blk 64..127 = layer 1, both 16 cols/block.

#define BB    16
#define SLEN  512
#define DH    1024
#define NBLK0 64

typedef __attribute__((ext_vector_type(8))) short short8;
typedef __attribute__((ext_vector_type(4))) float f32x4;

__device__ inline unsigned short f2bfbits(float x) {
  union { float f; unsigned u; } v; v.f = x;
  unsigned r = v.u + 0x7FFF + ((v.u >> 16) & 1);  // RNE
  return (unsigned short)(r >> 16);
}

// ---------------- zero flags ----------------
__global__ void zero_cnt_kernel(unsigned* cnt) {
  if (threadIdx.x < 128) cnt[threadIdx.x] = 0;
}

// ---------------- embedding gather ----------------
__global__ __launch_bounds__(256) void embed_kernel(const int* __restrict__ tokens,
                                                    const float* __restrict__ emb,
                                                    float* __restrict__ x0) {
  int idx = blockIdx.x * 256 + threadIdx.x;  // over 8192*128 float4s
  int r = idx >> 7, d4 = idx & 127;
  int tok = tokens[r];
  const float4* src = (const float4*)emb + (((size_t)tok) << 7) + d4;
  ((float4*)x0)[(((size_t)r) << 7) + d4] = *src;
}

// ---------------- xproj GEMM (layer 0 only): C[M][4096] = A[M][512] @ W_g + b_g ----------------
__global__ __launch_bounds__(256) void xproj_kernel(
    const float* __restrict__ A, int K,
    const float* __restrict__ Wi, const float* __restrict__ Wf,
    const float* __restrict__ Wg, const float* __restrict__ Wo,
    const float* __restrict__ bi, const float* __restrict__ bf,
    const float* __restrict__ bg, const float* __restrict__ bo,
    float* __restrict__ Cout)
{
  __shared__ float As[8][128];
  __shared__ float Bs[8][128];
  const int tid = threadIdx.x;
  const int bn = blockIdx.x;   // 0..31
  const int bm = blockIdx.y;   // 0..63
  const int m0 = bm * 128;
  const int n0 = bn * 128;
  const int g = n0 >> 10;
  const float* W    = (g == 0) ? Wi : (g == 1) ? Wf : (g == 2) ? Wg : Wo;
  const float* bias = (g == 0) ? bi : (g == 1) ? bf : (g == 2) ? bg : bo;
  const int col0 = n0 & 1023;
  const int tx = tid & 15, ty = tid >> 4;
  const int lr = tid >> 1, lh = tid & 1;          // A-tile loader
  const int lk = tid >> 5, ln = (tid & 31) << 2;  // B-tile loader

  float acc[8][8];
#pragma unroll
  for (int i = 0; i < 8; ++i)
#pragma unroll
    for (int j = 0; j < 8; ++j) acc[i][j] = 0.f;

  for (int k0 = 0; k0 < K; k0 += 8) {
    float4 av = *(const float4*)(A + (size_t)(m0 + lr) * K + k0 + lh * 4);
    float4 bv = *(const float4*)(W + (size_t)(k0 + lk) * 1024 + col0 + ln);
    As[lh * 4 + 0][lr] = av.x;
    As[lh * 4 + 1][lr] = av.y;
    As[lh * 4 + 2][lr] = av.z;
    As[lh * 4 + 3][lr] = av.w;
    *(float4*)&Bs[lk][ln] = bv;
    __syncthreads();
#pragma unroll
    for (int p = 0; p < 8; ++p) {
      float a[8], b[8];
      *(float4*)&a[0] = *(const float4*)&As[p][ty * 8];
      *(float4*)&a[4] = *(const float4*)&As[p][ty * 8 + 4];
      *(float4*)&b[0] = *(const float4*)&Bs[p][tx * 4];
      *(float4*)&b[4] = *(const float4*)&Bs[p][64 + tx * 4];
#pragma unroll
      for (int i = 0; i < 8; ++i)
#pragma unroll
        for (int j = 0; j < 8; ++j) acc[i][j] += a[i] * b[j];
    }
    __syncthreads();
  }
  float4 bA = *(const float4*)(bias + col0 + tx * 4);
  float4 bB = *(const float4*)(bias + col0 + 64 + tx * 4);
#pragma unroll
  for (int i = 0; i < 8; ++i) {
    int m = m0 + ty * 8 + i;
    float* crow = Cout + (((size_t)m) << 12) + n0;
    float4 o1 = make_float4(acc[i][0] + bA.x, acc[i][1] + bA.y, acc[i][2] + bA.z, acc[i][3] + bA.w);
    float4 o2 = make_float4(acc[i][4] + bB.x, acc[i][5] + bB.y, acc[i][6] + bB.z, acc[i][7] + bB.w);
    *(float4*)(crow + tx * 4) = o1;
    *(float4*)(crow + 64 + tx * 4) = o2;
  }
}

// ---------------- fused pipelined 2-layer LSTM recurrence ----------------
// 128 blocks x 512 threads (8 waves). Wave wv: gate = wv&3, K-half = wv>>2.
// blk 0..63: layer 0 cols blk*16 (K=1024 recurrent, halves of 512).
// blk 64..127: layer 1 cols (blk-64)*16 (K=2048: half 0 = h0(t), half 1 = h1(t-1)).
// h stores: sc0/sc1 write-through (relaxed agent atomic), lines written once;
// flags[0..63] = layer-0 step counters, flags[64..127] = layer-1.
__global__ __launch_bounds__(512, 2) void lstm_pipe(
    const float* __restrict__ xp,
    const float* __restrict__ W0i, const float* __restrict__ W0f,
    const float* __restrict__ W0g, const float* __restrict__ W0o,
    const float* __restrict__ W1i, const float* __restrict__ W1f,
    const float* __restrict__ W1g, const float* __restrict__ W1o,
    const float* __restrict__ b1i, const float* __restrict__ b1f,
    const float* __restrict__ b1g, const float* __restrict__ b1o,
    const float* __restrict__ Wfc,
    short* __restrict__ h0b16,
    short* __restrict__ h1b16,
    float2* __restrict__ part,       // [b*512+t][64] per-block head partials
    unsigned* __restrict__ flags)
{
  __shared__ float Pre[8][16][17];
  const int tid  = threadIdx.x;
  const int wv   = tid >> 6;         // 0..7
  const int g    = wv & 3;           // gate
  const int kh   = wv >> 2;          // K-half
  const int lane = tid & 63;
  const int q    = lane >> 4;
  const int n    = lane & 15;
  const int cb   = tid >> 4, cc = tid & 15;  // cell mapping (tid<256)

  if (blockIdx.x < NBLK0) {
    // ================= layer 0 =================
    const int c0 = blockIdx.x << 4;
    const float* Wsel = (g == 0) ? W0i : (g == 1) ? W0f : (g == 2) ? W0g : W0o;
    // 16 frags: rows 512 + kh*512 + kk*32 + q*8 + j of W0 (recurrent part)
    short8 wfrag[16];
#pragma unroll
    for (int kk = 0; kk < 16; ++kk)
#pragma unroll
      for (int j = 0; j < 8; ++j)
        wfrag[kk][j] = (short)f2bfbits(
            Wsel[(size_t)(512 + kh * 512 + kk * 32 + q * 8 + j) * 1024 + c0 + n]);

    float Creg = 0.f;
    const float* xpb = xp + ((size_t)g << 10) + c0 + n;
    f32x4 xpn = {0.f, 0.f, 0.f, 0.f};
    if (kh == 0) {
#pragma unroll
      for (int r = 0; r < 4; ++r)
        xpn[r] = xpb[((size_t)((q * 4 + r) * SLEN)) << 12];
    }

    for (int t = 0; t < SLEN; ++t) {
      f32x4 acc = (kh == 0) ? xpn : f32x4{0.f, 0.f, 0.f, 0.f};
      f32x4 acc2 = {0.f, 0.f, 0.f, 0.f};
      if (kh == 0 && t + 1 < SLEN) {
#pragma unroll
        for (int r = 0; r < 4; ++r)
          xpn[r] = xpb[((size_t)((q * 4 + r) * SLEN + t + 1)) << 12];
      }
      if (t > 0) {
        const short* hrow = h0b16 + (((size_t)(t - 1)) << 14) + n * 1024 + kh * 512 + q * 8;
#pragma unroll
        for (int kk = 0; kk < 16; kk += 2) {
          short8 a0 = *(const short8*)(hrow + kk * 32);
          short8 a1 = *(const short8*)(hrow + kk * 32 + 32);
          acc  = __builtin_amdgcn_mfma_f32_16x16x32_bf16(a0, wfrag[kk],     acc,  0, 0, 0);
          acc2 = __builtin_amdgcn_mfma_f32_16x16x32_bf16(a1, wfrag[kk + 1], acc2, 0, 0, 0);
        }
#pragma unroll
        for (int r = 0; r < 4; ++r) acc[r] += acc2[r];
      }
#pragma unroll
      for (int r = 0; r < 4; ++r) Pre[wv][q * 4 + r][n] = acc[r];
      __syncthreads();

      if (tid < 256) {
        float pI = Pre[0][cb][cc] + Pre[4][cb][cc];
        float pF = Pre[1][cb][cc] + Pre[5][cb][cc];
        float pG = Pre[2][cb][cc] + Pre[6][cb][cc];
        float pO = Pre[3][cb][cc] + Pre[7][cb][cc];
        float gI = 1.f / (1.f + __expf(-pI));
        float gF = 1.f / (1.f + __expf(-pF));
        float gG = tanhf(pG);
        float gO = 1.f / (1.f + __expf(-pO));
        Creg = gF * Creg + gI * gG;
        float h = gO * tanhf(Creg);

        unsigned mybits = (unsigned)f2bfbits(h);
        unsigned nbbits = (unsigned)__shfl_xor((int)mybits, 1, 64);
        if ((cc & 1) == 0) {
          unsigned pk = mybits | (nbbits << 16);
          __hip_atomic_store((unsigned*)(h0b16 + (((size_t)(t * 16 + cb)) << 10) + c0 + cc), pk,
                             __ATOMIC_RELAXED, __HIP_MEMORY_SCOPE_AGENT);
        }
      }
      __syncthreads();  // implicit vmcnt(0): h stores at coherence point

      if (tid == 0)
        __hip_atomic_store(&flags[blockIdx.x], (unsigned)(t + 1),
                           __ATOMIC_RELAXED, __HIP_MEMORY_SCOPE_AGENT);
      if (t + 1 < SLEN) {
        if (tid < 64) {
          const unsigned tgt = (unsigned)(t + 1);
          while (true) {
            unsigned v0 = __hip_atomic_load(&flags[tid], __ATOMIC_RELAXED,
                                            __HIP_MEMORY_SCOPE_AGENT);
            if (__all((int)(v0 >= tgt))) break;
            __builtin_amdgcn_s_sleep(1);
          }
        }
        __syncthreads();
      }
    }
  } else {
    // ================= layer 1 =================
    const int blk1 = blockIdx.x - NBLK0;
    const int c0 = blk1 << 4;
    const float* Wsel = (g == 0) ? W1i : (g == 1) ? W1f : (g == 2) ? W1g : W1o;
    const float* bsel = (g == 0) ? b1i : (g == 1) ? b1f : (g == 2) ? b1g : b1o;
    // 32 frags: rows kh*1024 + kk*32 + q*8 + j of W1 (kh=0: h0-input, kh=1: h1-rec)
    short8 wfrag[32];
#pragma unroll
    for (int kk = 0; kk < 32; ++kk)
#pragma unroll
      for (int j = 0; j < 8; ++j)
        wfrag[kk][j] = (short)f2bfbits(
            Wsel[(size_t)(kh * 1024 + kk * 32 + q * 8 + j) * 1024 + c0 + n]);
    const float bcol = (kh == 0) ? bsel[c0 + n] : 0.f;
    const float wfc0 = Wfc[(c0 + cc) * 2 + 0];
    const float wfc1 = Wfc[(c0 + cc) * 2 + 1];
    float Creg = 0.f;

    for (int t = 0; t < SLEN; ++t) {
      // wait for h0(t) (flag0 >= t+1) and h1(t-1) (flag1 >= t)
      if (tid < 64) {
        const unsigned tgt0 = (unsigned)(t + 1);
        const unsigned tgt1 = (unsigned)t;
        while (true) {
          unsigned v0 = __hip_atomic_load(&flags[tid], __ATOMIC_RELAXED,
                                          __HIP_MEMORY_SCOPE_AGENT);
          unsigned v1 = __hip_atomic_load(&flags[64 + tid], __ATOMIC_RELAXED,
                                          __HIP_MEMORY_SCOPE_AGENT);
          if (__all((int)(v0 >= tgt0 && v1 >= tgt1))) break;
          __builtin_amdgcn_s_sleep(1);
        }
      }
      __syncthreads();

      f32x4 acc, acc2 = {0.f, 0.f, 0.f, 0.f};
#pragma unroll
      for (int r = 0; r < 4; ++r) acc[r] = bcol;

      if (kh == 0) {
        // A = h0(t)
        const short* xrow = h0b16 + (((size_t)t) << 14) + n * 1024 + q * 8;
#pragma unroll
        for (int kk = 0; kk < 32; kk += 2) {
          short8 a0 = *(const short8*)(xrow + kk * 32);
          short8 a1 = *(const short8*)(xrow + kk * 32 + 32);
          acc  = __builtin_amdgcn_mfma_f32_16x16x32_bf16(a0, wfrag[kk],     acc,  0, 0, 0);
          acc2 = __builtin_amdgcn_mfma_f32_16x16x32_bf16(a1, wfrag[kk + 1], acc2, 0, 0, 0);
        }
      } else if (t > 0) {
        // A = h1(t-1)
        const short* hrow = h1b16 + (((size_t)(t - 1)) << 14) + n * 1024 + q * 8;
#pragma unroll
        for (int kk = 0; kk < 32; kk += 2) {
          short8 a0 = *(const short8*)(hrow + kk * 32);
          short8 a1 = *(const short8*)(hrow + kk * 32 + 32);
          acc  = __builtin_amdgcn_mfma_f32_16x16x32_bf16(a0, wfrag[kk],     acc,  0, 0, 0);
          acc2 = __builtin_amdgcn_mfma_f32_16x16x32_bf16(a1, wfrag[kk + 1], acc2, 0, 0, 0);
        }
      }
#pragma unroll
      for (int r = 0; r < 4; ++r) acc[r] += acc2[r];

#pragma unroll
      for (int r = 0; r < 4; ++r) Pre[wv][q * 4 + r][n] = acc[r];
      __syncthreads();

      if (tid < 256) {
        float pI = Pre[0][cb][cc] + Pre[4][cb][cc];
        float pF = Pre[1][cb][cc] + Pre[5][cb][cc];
        float pG = Pre[2][cb][cc] + Pre[6][cb][cc];
        float pO = Pre[3][cb][cc] + Pre[7][cb][cc];
        float gI = 1.f / (1.f + __expf(-pI));
        float gF = 1.f / (1.f + __expf(-pF));
        float gG = tanhf(pG);
        float gO = 1.f / (1.f + __expf(-pO));
        Creg = gF * Creg + gI * gG;
        float h = gO * tanhf(Creg);

        // head partial: sum over this block's 16 cols for row (b=cb, t)
        float p0 = h * wfc0, p1 = h * wfc1;
#pragma unroll
        for (int m = 1; m < 16; m <<= 1) {
          p0 += __shfl_xor(p0, m, 64);
          p1 += __shfl_xor(p1, m, 64);
        }
        if (cc == 0)
          part[(size_t)(cb * SLEN + t) * 64 + blk1] = make_float2(p0, p1);

        unsigned mybits = (unsigned)f2bfbits(h);
        unsigned nbbits = (unsigned)__shfl_xor((int)mybits, 1, 64);
        if ((cc & 1) == 0) {
          unsigned pk = mybits | (nbbits << 16);
          __hip_atomic_store((unsigned*)(h1b16 + (((size_t)(t * 16 + cb)) << 10) + c0 + cc), pk,
                             __ATOMIC_RELAXED, __HIP_MEMORY_SCOPE_AGENT);
        }
      }
      __syncthreads();  // drains stores

      if (tid == 0)
        __hip_atomic_store(&flags[64 + blk1], (unsigned)(t + 1),
                           __ATOMIC_RELAXED, __HIP_MEMORY_SCOPE_AGENT);
    }
  }
}

// ---------------- finalize: 64-way partial sum + bias + log_softmax ----------------
__global__ __launch_bounds__(256) void finalize_kernel(const float2* __restrict__ part,
                                                       const float* __restrict__ bfc,
                                                       float* __restrict__ out)
{
  const int lane = threadIdx.x & 63;
  const int row = blockIdx.x * 4 + (threadIdx.x >> 6);
  float2 v = part[(size_t)row * 64 + lane];
  float s0 = v.x, s1 = v.y;
#pragma unroll
  for (int off = 32; off > 0; off >>= 1) {
    s0 += __shfl_down(s0, off);
    s1 += __shfl_down(s1, off);
  }
  if (lane == 0) {
    s0 += bfc[0];
    s1 += bfc[1];
    float m = fmaxf(s0, s1);
    float lse = m + logf(expf(s0 - m) + expf(s1 - m));
    out[((size_t)row << 1) + 0] = s0 - lse;
    out[((size_t)row << 1) + 1] = s1 - lse;
  }
}

extern "C" void kernel_launch(void* const* d_in, const int* in_sizes, int n_in,
                              void* d_out, int out_size, void* d_ws, size_t ws_size,
                              hipStream_t stream)
{
  const int*   tokens = (const int*)d_in[0];
  const float* emb = (const float*)d_in[1];
  const float* W0i = (const float*)d_in[2];
  const float* b0i = (const float*)d_in[3];
  const float* W0f = (const float*)d_in[4];
  const float* b0f = (const float*)d_in[5];
  const float* W0g = (const float*)d_in[6];
  const float* b0g = (const float*)d_in[7];
  const float* W0o = (const float*)d_in[8];
  const float* b0o = (const float*)d_in[9];
  const float* W1i = (const float*)d_in[10];
  const float* b1i = (const float*)d_in[11];
  const float* W1f = (const float*)d_in[12];
  const float* b1f = (const float*)d_in[13];
  const float* W1g = (const float*)d_in[14];
  const float* b1g = (const float*)d_in[15];
  const float* W1o = (const float*)d_in[16];
  const float* b1o = (const float*)d_in[17];
  const float* Wfc = (const float*)d_in[18];
  const float* bfc = (const float*)d_in[19];
  float* out = (float*)d_out;

  float* ws = (float*)d_ws;
  float* x0 = ws;                               // 16MB embed out; aliased as h0b16
  float* hA = x0 + (size_t)8192 * 512;          // 32MB region: h1b16 (16MB) + part (4MB)
  float* xp = hA + (size_t)8192 * 1024;         // 128MB layer-0 x-preacts
  unsigned* flags = (unsigned*)(xp + (size_t)8192 * 4096);
  short*  h0b16 = (short*)x0;                   // bf16 [t][b][1024]
  short*  h1b16 = (short*)hA;                   // bf16 [t][b][1024]
  float2* part  = (float2*)(hA + (size_t)8192 * 512);  // [8192][64] float2

  zero_cnt_kernel<<<1, 128, 0, stream>>>(flags);
  embed_kernel<<<4096, 256, 0, stream>>>(tokens, emb, x0);
  xproj_kernel<<<dim3(32, 64), 256, 0, stream>>>(x0, 512, W0i, W0f, W0g, W0o,
                                                 b0i, b0f, b0g, b0o, xp);
  lstm_pipe<<<128, 512, 0, stream>>>(xp,
                                     W0i, W0f, W0g, W0o,
                                     W1i, W1f, W1g, W1o,
                                     b1i, b1f, b1g, b1o,
                                     Wfc, h0b16, h1b16, part, flags);
  finalize_kernel<<<2048, 256, 0, stream>>>(part, bfc, out);
}